// Round 4
// baseline (247.568 us; speedup 1.0000x reference)
//
#include <hip/hip_runtime.h>

#define GAMMA_C 0.2f

// pos = ALPHA     * ln2 * s2 * exp2(-g*a2)
// neg = (1-ALPHA) * ln2 * a2 * exp2(-g*s2)
// where s2 = log2(1 + exp2(-x*log2e)), a2 = x*log2e + s2.
#define L2E_C 1.4426950408889634f
#define CPOS_C 0.41588830833596715f  // 0.6 * ln2
#define CNEG_C 0.27725887222397810f  // 0.4 * ln2

__device__ __forceinline__ float focal_elem(float x, int t) {
    float xl = x * L2E_C;
    float e  = __builtin_amdgcn_exp2f(-xl);       // exp(-x)
    float s2 = __builtin_amdgcn_logf(1.0f + e);   // softplus(-x)/ln2
    float a2 = xl + s2;                           // (x + softplus(-x))/ln2
    bool ispos = (t == 1);
    float earg = ispos ? a2 : s2;
    float fac  = ispos ? s2 : a2;
    float cf   = ispos ? CPOS_C : CNEG_C;
    float ex   = __builtin_amdgcn_exp2f(-GAMMA_C * earg);
    return cf * fac * ex;
}

__device__ __forceinline__ float focal_vec4(float4 x4, int4 t4) {
    float r = focal_elem(x4.x, t4.x);
    r += focal_elem(x4.y, t4.y);
    r += focal_elem(x4.z, t4.z);
    r += focal_elem(x4.w, t4.w);
    return r;
}

// Fused: grid-stride partial sums + last-block final reduce.
// Cross-XCD visibility of partial[] is guaranteed via AGENT-scope atomics
// (per-XCD L2s are not coherent; plain stores could be stale for the reader).
__global__ __launch_bounds__(256) void focal_fused_kernel(
    const float4* __restrict__ logits4,
    const int4* __restrict__ target4,
    float* __restrict__ partial,
    unsigned* __restrict__ ctr,
    long long nvec,
    const float* __restrict__ logits_s,   // scalar views for tail
    const int* __restrict__ target_s,
    long long n,
    float inv_count,
    float* __restrict__ out)
{
    const long long stride = (long long)gridDim.x * blockDim.x;
    long long i = (long long)blockIdx.x * blockDim.x + threadIdx.x;

    float a0 = 0.0f, a1 = 0.0f, a2 = 0.0f, a3 = 0.0f;

    for (; i + 3 * stride < nvec; i += 4 * stride) {
        float4 x0 = logits4[i];
        float4 x1 = logits4[i + stride];
        float4 x2 = logits4[i + 2 * stride];
        float4 x3 = logits4[i + 3 * stride];
        int4   t0 = target4[i];
        int4   t1 = target4[i + stride];
        int4   t2 = target4[i + 2 * stride];
        int4   t3 = target4[i + 3 * stride];
        a0 += focal_vec4(x0, t0);
        a1 += focal_vec4(x1, t1);
        a2 += focal_vec4(x2, t2);
        a3 += focal_vec4(x3, t3);
    }
    for (; i < nvec; i += stride)
        a0 += focal_vec4(logits4[i], target4[i]);

    float acc = (a0 + a1) + (a2 + a3);

    // Tail (n % 4 != 0) — no-op for this problem shape.
    if (blockIdx.x == 0 && threadIdx.x == 0) {
        for (long long k = nvec * 4; k < n; ++k)
            acc += focal_elem(logits_s[k], target_s[k]);
    }

    // Wave (64-lane) reduction
#pragma unroll
    for (int off = 32; off > 0; off >>= 1)
        acc += __shfl_down(acc, off, 64);

    __shared__ float smem[4];
    __shared__ bool is_last;
    int lane = threadIdx.x & 63;
    int wid  = threadIdx.x >> 6;
    if (lane == 0) smem[wid] = acc;
    __syncthreads();

    if (threadIdx.x == 0) {
        float bsum = smem[0] + smem[1] + smem[2] + smem[3];
        // Device-scope store so the last block (possibly another XCD) sees it.
        __hip_atomic_store(&partial[blockIdx.x], bsum,
                           __ATOMIC_RELEASE, __HIP_MEMORY_SCOPE_AGENT);
        unsigned old = __hip_atomic_fetch_add(ctr, 1u,
                           __ATOMIC_ACQ_REL, __HIP_MEMORY_SCOPE_AGENT);
        is_last = (old == gridDim.x - 1u);
    }
    __syncthreads();

    if (is_last) {
        // Fixed-order reduce of per-block partials -> bit-deterministic.
        float facc = 0.0f;
        for (unsigned k = threadIdx.x; k < gridDim.x; k += 256)
            facc += __hip_atomic_load(&partial[k],
                        __ATOMIC_ACQUIRE, __HIP_MEMORY_SCOPE_AGENT);
#pragma unroll
        for (int off = 32; off > 0; off >>= 1)
            facc += __shfl_down(facc, off, 64);
        __syncthreads();   // smem reuse
        if (lane == 0) smem[wid] = facc;
        __syncthreads();
        if (threadIdx.x == 0)
            out[0] = (smem[0] + smem[1] + smem[2] + smem[3]) * inv_count;
    }
}

extern "C" void kernel_launch(void* const* d_in, const int* in_sizes, int n_in,
                              void* d_out, int out_size, void* d_ws, size_t ws_size,
                              hipStream_t stream) {
    const float* logits = (const float*)d_in[0];
    const int*   target = (const int*)d_in[1];
    long long n = (long long)in_sizes[0];     // N*C = 41,943,040
    long long nvec = n / 4;

    unsigned* ctr   = (unsigned*)d_ws;
    float* partial  = (float*)((char*)d_ws + 128);
    const int nblocks = 2048;                 // 256 CU x 8 blocks, exact fill
    const int nthreads = 256;

    hipMemsetAsync(ctr, 0, sizeof(unsigned), stream);
    focal_fused_kernel<<<nblocks, nthreads, 0, stream>>>(
        (const float4*)logits, (const int4*)target, partial, ctr, nvec,
        logits, target, n, 1.0f / (float)n, (float*)d_out);
}

// Round 5
// 69.297 us; speedup vs baseline: 3.5726x; 3.5726x over previous
//
#include <hip/hip_runtime.h>

#define GAMMA_C 0.2f

// pos = ALPHA     * ln2 * s2 * exp2(-g*a2)
// neg = (1-ALPHA) * ln2 * a2 * exp2(-g*s2)
// where s2 = log2(1 + exp2(-x*log2e)), a2 = x*log2e + s2.
#define L2E_C 1.4426950408889634f
#define CPOS_C 0.41588830833596715f  // 0.6 * ln2
#define CNEG_C 0.27725887222397810f  // 0.4 * ln2

typedef float __attribute__((ext_vector_type(4))) f32x4;
typedef int   __attribute__((ext_vector_type(4))) i32x4;

__device__ __forceinline__ float focal_elem(float x, int t) {
    float xl = x * L2E_C;
    float e  = __builtin_amdgcn_exp2f(-xl);       // exp(-x)
    float s2 = __builtin_amdgcn_logf(1.0f + e);   // softplus(-x)/ln2
    float a2 = xl + s2;                           // (x + softplus(-x))/ln2
    bool ispos = (t == 1);
    float earg = ispos ? a2 : s2;
    float fac  = ispos ? s2 : a2;
    float cf   = ispos ? CPOS_C : CNEG_C;
    float ex   = __builtin_amdgcn_exp2f(-GAMMA_C * earg);
    return cf * fac * ex;
}

__device__ __forceinline__ float focal_vec4(f32x4 x4, i32x4 t4) {
    float r = focal_elem(x4.x, t4.x);
    r += focal_elem(x4.y, t4.y);
    r += focal_elem(x4.z, t4.z);
    r += focal_elem(x4.w, t4.w);
    return r;
}

// Stage 1: grid-stride over vec4, non-temporal streaming loads,
// per-block partial sum to ws.
__global__ __launch_bounds__(256) void focal_partial_kernel(
    const f32x4* __restrict__ logits4,
    const i32x4* __restrict__ target4,
    float* __restrict__ partial,
    long long nvec,
    const float* __restrict__ logits_s,   // scalar views for tail
    const int* __restrict__ target_s,
    long long n)
{
    const long long stride = (long long)gridDim.x * blockDim.x;
    long long i = (long long)blockIdx.x * blockDim.x + threadIdx.x;

    float a0 = 0.0f, a1 = 0.0f, a2 = 0.0f, a3 = 0.0f;

    for (; i + 3 * stride < nvec; i += 4 * stride) {
        f32x4 x0 = __builtin_nontemporal_load(&logits4[i]);
        f32x4 x1 = __builtin_nontemporal_load(&logits4[i + stride]);
        f32x4 x2 = __builtin_nontemporal_load(&logits4[i + 2 * stride]);
        f32x4 x3 = __builtin_nontemporal_load(&logits4[i + 3 * stride]);
        i32x4 t0 = __builtin_nontemporal_load(&target4[i]);
        i32x4 t1 = __builtin_nontemporal_load(&target4[i + stride]);
        i32x4 t2 = __builtin_nontemporal_load(&target4[i + 2 * stride]);
        i32x4 t3 = __builtin_nontemporal_load(&target4[i + 3 * stride]);
        a0 += focal_vec4(x0, t0);
        a1 += focal_vec4(x1, t1);
        a2 += focal_vec4(x2, t2);
        a3 += focal_vec4(x3, t3);
    }
    for (; i < nvec; i += stride) {
        f32x4 x = __builtin_nontemporal_load(&logits4[i]);
        i32x4 t = __builtin_nontemporal_load(&target4[i]);
        a0 += focal_vec4(x, t);
    }

    float acc = (a0 + a1) + (a2 + a3);

    // Tail (n % 4 != 0) — no-op for this problem shape.
    if (blockIdx.x == 0 && threadIdx.x == 0) {
        for (long long k = nvec * 4; k < n; ++k)
            acc += focal_elem(logits_s[k], target_s[k]);
    }

    // Wave (64-lane) reduction
#pragma unroll
    for (int off = 32; off > 0; off >>= 1)
        acc += __shfl_down(acc, off, 64);

    __shared__ float smem[4];
    int lane = threadIdx.x & 63;
    int wid  = threadIdx.x >> 6;
    if (lane == 0) smem[wid] = acc;
    __syncthreads();
    if (threadIdx.x == 0)
        partial[blockIdx.x] = smem[0] + smem[1] + smem[2] + smem[3];
}

// Stage 2: deterministic reduce of per-block partials, apply mean, write out.
__global__ __launch_bounds__(256) void focal_final_kernel(
    const float* __restrict__ partial,
    int nblocks,
    float inv_count,
    float* __restrict__ out)
{
    float acc = 0.0f;
    for (int i = threadIdx.x; i < nblocks; i += 256)
        acc += partial[i];

#pragma unroll
    for (int off = 32; off > 0; off >>= 1)
        acc += __shfl_down(acc, off, 64);

    __shared__ float smem[4];
    int lane = threadIdx.x & 63;
    int wid  = threadIdx.x >> 6;
    if (lane == 0) smem[wid] = acc;
    __syncthreads();
    if (threadIdx.x == 0)
        out[0] = (smem[0] + smem[1] + smem[2] + smem[3]) * inv_count;
}

extern "C" void kernel_launch(void* const* d_in, const int* in_sizes, int n_in,
                              void* d_out, int out_size, void* d_ws, size_t ws_size,
                              hipStream_t stream) {
    const float* logits = (const float*)d_in[0];
    const int*   target = (const int*)d_in[1];
    long long n = (long long)in_sizes[0];     // N*C = 41,943,040
    long long nvec = n / 4;

    float* partial = (float*)d_ws;
    const int nblocks = 2048;                 // 256 CU x 8 blocks, exact fill
    const int nthreads = 256;

    focal_partial_kernel<<<nblocks, nthreads, 0, stream>>>(
        (const f32x4*)logits, (const i32x4*)target, partial, nvec,
        logits, target, n);
    focal_final_kernel<<<1, nthreads, 0, stream>>>(
        partial, nblocks, 1.0f / (float)n, (float*)d_out);
}

// Round 6
// 64.239 us; speedup vs baseline: 3.8539x; 1.0787x over previous
//
#include <hip/hip_runtime.h>

#define GAMMA_C 0.2f

// pos = ALPHA     * ln2 * s2 * exp2(-g*a2)
// neg = (1-ALPHA) * ln2 * a2 * exp2(-g*s2)
// where s2 = log2(1 + exp2(-x*log2e)), a2 = x*log2e + s2.
#define L2E_C 1.4426950408889634f
#define CPOS_C 0.41588830833596715f  // 0.6 * ln2
#define CNEG_C 0.27725887222397810f  // 0.4 * ln2

typedef float __attribute__((ext_vector_type(4))) f32x4;
typedef int   __attribute__((ext_vector_type(4))) i32x4;

__device__ __forceinline__ float focal_elem(float x, int t) {
    float xl = x * L2E_C;
    float e  = __builtin_amdgcn_exp2f(-xl);       // exp(-x)
    float s2 = __builtin_amdgcn_logf(1.0f + e);   // softplus(-x)/ln2
    float a2 = xl + s2;                           // (x + softplus(-x))/ln2
    bool ispos = (t == 1);
    float earg = ispos ? a2 : s2;
    float fac  = ispos ? s2 : a2;
    float cf   = ispos ? CPOS_C : CNEG_C;
    float ex   = __builtin_amdgcn_exp2f(-GAMMA_C * earg);
    return cf * fac * ex;
}

__device__ __forceinline__ float focal_vec4(f32x4 x4, i32x4 t4) {
    float r = focal_elem(x4.x, t4.x);
    r += focal_elem(x4.y, t4.y);
    r += focal_elem(x4.z, t4.z);
    r += focal_elem(x4.w, t4.w);
    return r;
}

// Stage 1: grid-stride, explicit 2-deep software pipeline:
// prefetch next {2x f32x4, 2x i32x4} while computing current.
__global__ __launch_bounds__(256) void focal_partial_kernel(
    const f32x4* __restrict__ logits4,
    const i32x4* __restrict__ target4,
    float* __restrict__ partial,
    long long nvec,
    const float* __restrict__ logits_s,   // scalar views for tail
    const int* __restrict__ target_s,
    long long n)
{
    const long long stride = (long long)gridDim.x * blockDim.x;
    long long ip = (long long)blockIdx.x * blockDim.x + threadIdx.x;

    float a0 = 0.0f, a1 = 0.0f, a2 = 0.0f, a3 = 0.0f;

    // --- pipelined pair loop ---
    bool have = (ip + stride < nvec);
    f32x4 cx0, cx1; i32x4 ct0, ct1;
    if (have) {
        cx0 = logits4[ip];
        cx1 = logits4[ip + stride];
        ct0 = target4[ip];
        ct1 = target4[ip + stride];
    }
    while (have) {
        long long inx = ip + 2 * stride;
        bool hnext = (inx + stride < nvec);
        f32x4 nx0, nx1; i32x4 nt0, nt1;
        if (hnext) {
            // issued before the dependent compute below -> in flight under it
            nx0 = logits4[inx];
            nx1 = logits4[inx + stride];
            nt0 = target4[inx];
            nt1 = target4[inx + stride];
        }
        a0 += focal_vec4(cx0, ct0);
        a1 += focal_vec4(cx1, ct1);
        cx0 = nx0; cx1 = nx1; ct0 = nt0; ct1 = nt1;
        ip = inx; have = hnext;
    }
    // remainder (0 or 1 vec4 groups for non-pair-divisible shapes)
    for (; ip < nvec; ip += stride)
        a2 += focal_vec4(logits4[ip], target4[ip]);

    float acc = (a0 + a1) + (a2 + a3);

    // Tail (n % 4 != 0) — no-op for this problem shape.
    if (blockIdx.x == 0 && threadIdx.x == 0) {
        for (long long k = nvec * 4; k < n; ++k)
            acc += focal_elem(logits_s[k], target_s[k]);
    }

    // Wave (64-lane) reduction
#pragma unroll
    for (int off = 32; off > 0; off >>= 1)
        acc += __shfl_down(acc, off, 64);

    __shared__ float smem[4];
    int lane = threadIdx.x & 63;
    int wid  = threadIdx.x >> 6;
    if (lane == 0) smem[wid] = acc;
    __syncthreads();
    if (threadIdx.x == 0)
        partial[blockIdx.x] = smem[0] + smem[1] + smem[2] + smem[3];
}

// Stage 2: deterministic reduce of per-block partials, apply mean, write out.
__global__ __launch_bounds__(256) void focal_final_kernel(
    const float* __restrict__ partial,
    int nblocks,
    float inv_count,
    float* __restrict__ out)
{
    float acc = 0.0f;
    for (int i = threadIdx.x; i < nblocks; i += 256)
        acc += partial[i];

#pragma unroll
    for (int off = 32; off > 0; off >>= 1)
        acc += __shfl_down(acc, off, 64);

    __shared__ float smem[4];
    int lane = threadIdx.x & 63;
    int wid  = threadIdx.x >> 6;
    if (lane == 0) smem[wid] = acc;
    __syncthreads();
    if (threadIdx.x == 0)
        out[0] = (smem[0] + smem[1] + smem[2] + smem[3]) * inv_count;
}

extern "C" void kernel_launch(void* const* d_in, const int* in_sizes, int n_in,
                              void* d_out, int out_size, void* d_ws, size_t ws_size,
                              hipStream_t stream) {
    const float* logits = (const float*)d_in[0];
    const int*   target = (const int*)d_in[1];
    long long n = (long long)in_sizes[0];     // N*C = 41,943,040
    long long nvec = n / 4;

    float* partial = (float*)d_ws;
    const int nblocks = 2048;                 // 256 CU x 8 blocks, exact fill
    const int nthreads = 256;

    focal_partial_kernel<<<nblocks, nthreads, 0, stream>>>(
        (const f32x4*)logits, (const i32x4*)target, partial, nvec,
        logits, target, n);
    focal_final_kernel<<<1, nthreads, 0, stream>>>(
        partial, nblocks, 1.0f / (float)n, (float*)d_out);
}

// Round 7
// 60.500 us; speedup vs baseline: 4.0920x; 1.0618x over previous
//
#include <hip/hip_runtime.h>

#define GAMMA_C 0.2f

// pos = ALPHA     * ln2 * s2 * exp2(-g*a2)
// neg = (1-ALPHA) * ln2 * a2 * exp2(-g*s2)
// where s2 = log2(1 + exp2(-x*log2e)), a2 = x*log2e + s2.
#define L2E_C 1.4426950408889634f
#define CPOS_C 0.41588830833596715f  // 0.6 * ln2
#define CNEG_C 0.27725887222397810f  // 0.4 * ln2

typedef float __attribute__((ext_vector_type(4))) f32x4;
typedef int   __attribute__((ext_vector_type(4))) i32x4;

__device__ __forceinline__ float focal_elem(float x, int t) {
    float xl = x * L2E_C;
    float e  = __builtin_amdgcn_exp2f(-xl);       // exp(-x)
    float s2 = __builtin_amdgcn_logf(1.0f + e);   // softplus(-x)/ln2
    float a2 = xl + s2;                           // (x + softplus(-x))/ln2
    bool ispos = (t == 1);
    float earg = ispos ? a2 : s2;
    float fac  = ispos ? s2 : a2;
    float cf   = ispos ? CPOS_C : CNEG_C;
    float ex   = __builtin_amdgcn_exp2f(-GAMMA_C * earg);
    return cf * fac * ex;
}

__device__ __forceinline__ float focal_vec4(f32x4 x4, i32x4 t4) {
    float r = focal_elem(x4.x, t4.x);
    r += focal_elem(x4.y, t4.y);
    r += focal_elem(x4.z, t4.z);
    r += focal_elem(x4.w, t4.w);
    return r;
}

// Stage 1: block-contiguous partition. Each block sweeps one contiguous
// vec4 range of both streams (80 KB logits + 80 KB target for this shape),
// waves marching linearly -> maximal DRAM row locality, 32-bit indexing.
__global__ __launch_bounds__(256) void focal_partial_kernel(
    const f32x4* __restrict__ logits4,
    const i32x4* __restrict__ target4,
    float* __restrict__ partial,
    long long nvec,
    const float* __restrict__ logits_s,   // scalar views for tail
    const int* __restrict__ target_s,
    long long n)
{
    const long long chunk = (nvec + gridDim.x - 1) / gridDim.x;
    const long long start = (long long)blockIdx.x * chunk;
    long long end_ll = start + chunk;
    if (end_ll > nvec) end_ll = nvec;
    const int len = (int)(end_ll > start ? end_ll - start : 0);

    const f32x4* __restrict__ lg = logits4 + start;
    const i32x4* __restrict__ tg = target4 + start;

    float a0 = 0.0f, a1 = 0.0f, a2 = 0.0f, a3 = 0.0f;

    int k = threadIdx.x;
    // 4-deep unroll: 8 independent 16B loads in flight, contiguous 16 KB
    // window per stream per iteration across the block.
    for (; k + 768 < len; k += 1024) {
        f32x4 x0 = lg[k];
        f32x4 x1 = lg[k + 256];
        f32x4 x2 = lg[k + 512];
        f32x4 x3 = lg[k + 768];
        i32x4 t0 = tg[k];
        i32x4 t1 = tg[k + 256];
        i32x4 t2 = tg[k + 512];
        i32x4 t3 = tg[k + 768];
        a0 += focal_vec4(x0, t0);
        a1 += focal_vec4(x1, t1);
        a2 += focal_vec4(x2, t2);
        a3 += focal_vec4(x3, t3);
    }
    for (; k < len; k += 256)
        a0 += focal_vec4(lg[k], tg[k]);

    float acc = (a0 + a1) + (a2 + a3);

    // Tail (n % 4 != 0) — no-op for this problem shape.
    if (blockIdx.x == 0 && threadIdx.x == 0) {
        for (long long q = nvec * 4; q < n; ++q)
            acc += focal_elem(logits_s[q], target_s[q]);
    }

    // Wave (64-lane) reduction
#pragma unroll
    for (int off = 32; off > 0; off >>= 1)
        acc += __shfl_down(acc, off, 64);

    __shared__ float smem[4];
    int lane = threadIdx.x & 63;
    int wid  = threadIdx.x >> 6;
    if (lane == 0) smem[wid] = acc;
    __syncthreads();
    if (threadIdx.x == 0)
        partial[blockIdx.x] = smem[0] + smem[1] + smem[2] + smem[3];
}

// Stage 2: deterministic reduce of per-block partials, apply mean, write out.
__global__ __launch_bounds__(256) void focal_final_kernel(
    const float* __restrict__ partial,
    int nblocks,
    float inv_count,
    float* __restrict__ out)
{
    float acc = 0.0f;
    for (int i = threadIdx.x; i < nblocks; i += 256)
        acc += partial[i];

#pragma unroll
    for (int off = 32; off > 0; off >>= 1)
        acc += __shfl_down(acc, off, 64);

    __shared__ float smem[4];
    int lane = threadIdx.x & 63;
    int wid  = threadIdx.x >> 6;
    if (lane == 0) smem[wid] = acc;
    __syncthreads();
    if (threadIdx.x == 0)
        out[0] = (smem[0] + smem[1] + smem[2] + smem[3]) * inv_count;
}

extern "C" void kernel_launch(void* const* d_in, const int* in_sizes, int n_in,
                              void* d_out, int out_size, void* d_ws, size_t ws_size,
                              hipStream_t stream) {
    const float* logits = (const float*)d_in[0];
    const int*   target = (const int*)d_in[1];
    long long n = (long long)in_sizes[0];     // N*C = 41,943,040
    long long nvec = n / 4;

    float* partial = (float*)d_ws;
    const int nblocks = 2048;                 // 256 CU x 8 blocks, exact fill
    const int nthreads = 256;

    focal_partial_kernel<<<nblocks, nthreads, 0, stream>>>(
        (const f32x4*)logits, (const i32x4*)target, partial, nvec,
        logits, target, n);
    focal_final_kernel<<<1, nthreads, 0, stream>>>(
        partial, nblocks, 1.0f / (float)n, (float*)d_out);
}

// Round 8
// 60.092 us; speedup vs baseline: 4.1198x; 1.0068x over previous
//
#include <hip/hip_runtime.h>

#define GAMMA_C 0.2f

// pos = ALPHA     * ln2 * s2 * exp2(-g*a2)
// neg = (1-ALPHA) * ln2 * a2 * exp2(-g*s2)
// where s2 = log2(1 + exp2(-x*log2e)), a2 = x*log2e + s2.
#define L2E_C 1.4426950408889634f
#define CPOS_C 0.41588830833596715f  // 0.6 * ln2
#define CNEG_C 0.27725887222397810f  // 0.4 * ln2

typedef float __attribute__((ext_vector_type(4))) f32x4;
typedef int   __attribute__((ext_vector_type(4))) i32x4;

__device__ __forceinline__ float focal_elem(float x, int t) {
    float xl = x * L2E_C;
    float e  = __builtin_amdgcn_exp2f(-xl);       // exp(-x)
    float s2 = __builtin_amdgcn_logf(1.0f + e);   // softplus(-x)/ln2
    float a2 = xl + s2;                           // (x + softplus(-x))/ln2
    bool ispos = (t == 1);
    float earg = ispos ? a2 : s2;
    float fac  = ispos ? s2 : a2;
    float cf   = ispos ? CPOS_C : CNEG_C;
    float ex   = __builtin_amdgcn_exp2f(-GAMMA_C * earg);
    return cf * fac * ex;
}

__device__ __forceinline__ float focal_vec4(f32x4 x4, i32x4 t4) {
    float r = focal_elem(x4.x, t4.x);
    r += focal_elem(x4.y, t4.y);
    r += focal_elem(x4.z, t4.z);
    r += focal_elem(x4.w, t4.w);
    return r;
}

// Stage 1: block-contiguous partition, 1024 blocks (160 KB contiguous sweep
// per stream per block -> fewer, longer DRAM streams), 8-deep unroll
// (16 outstanding 16B loads/thread). For this shape: len=10240 vec4,
// exactly 5 unrolled iterations, no remainder.
__global__ __launch_bounds__(256) void focal_partial_kernel(
    const f32x4* __restrict__ logits4,
    const i32x4* __restrict__ target4,
    float* __restrict__ partial,
    long long nvec,
    const float* __restrict__ logits_s,   // scalar views for tail
    const int* __restrict__ target_s,
    long long n)
{
    const long long chunk = (nvec + gridDim.x - 1) / gridDim.x;
    const long long start = (long long)blockIdx.x * chunk;
    long long end_ll = start + chunk;
    if (end_ll > nvec) end_ll = nvec;
    const int len = (int)(end_ll > start ? end_ll - start : 0);

    const f32x4* __restrict__ lg = logits4 + start;
    const i32x4* __restrict__ tg = target4 + start;

    float a0 = 0.0f, a1 = 0.0f, a2 = 0.0f, a3 = 0.0f;

    int k = threadIdx.x;
    for (; k + 1792 < len; k += 2048) {
        f32x4 x0 = lg[k];
        f32x4 x1 = lg[k + 256];
        f32x4 x2 = lg[k + 512];
        f32x4 x3 = lg[k + 768];
        f32x4 x4 = lg[k + 1024];
        f32x4 x5 = lg[k + 1280];
        f32x4 x6 = lg[k + 1536];
        f32x4 x7 = lg[k + 1792];
        i32x4 t0 = tg[k];
        i32x4 t1 = tg[k + 256];
        i32x4 t2 = tg[k + 512];
        i32x4 t3 = tg[k + 768];
        i32x4 t4 = tg[k + 1024];
        i32x4 t5 = tg[k + 1280];
        i32x4 t6 = tg[k + 1536];
        i32x4 t7 = tg[k + 1792];
        a0 += focal_vec4(x0, t0);
        a1 += focal_vec4(x1, t1);
        a2 += focal_vec4(x2, t2);
        a3 += focal_vec4(x3, t3);
        a0 += focal_vec4(x4, t4);
        a1 += focal_vec4(x5, t5);
        a2 += focal_vec4(x6, t6);
        a3 += focal_vec4(x7, t7);
    }
    for (; k < len; k += 256)
        a0 += focal_vec4(lg[k], tg[k]);

    float acc = (a0 + a1) + (a2 + a3);

    // Tail (n % 4 != 0) — no-op for this problem shape.
    if (blockIdx.x == 0 && threadIdx.x == 0) {
        for (long long q = nvec * 4; q < n; ++q)
            acc += focal_elem(logits_s[q], target_s[q]);
    }

    // Wave (64-lane) reduction
#pragma unroll
    for (int off = 32; off > 0; off >>= 1)
        acc += __shfl_down(acc, off, 64);

    __shared__ float smem[4];
    int lane = threadIdx.x & 63;
    int wid  = threadIdx.x >> 6;
    if (lane == 0) smem[wid] = acc;
    __syncthreads();
    if (threadIdx.x == 0)
        partial[blockIdx.x] = smem[0] + smem[1] + smem[2] + smem[3];
}

// Stage 2: deterministic reduce of per-block partials, apply mean, write out.
__global__ __launch_bounds__(256) void focal_final_kernel(
    const float* __restrict__ partial,
    int nblocks,
    float inv_count,
    float* __restrict__ out)
{
    float acc = 0.0f;
    for (int i = threadIdx.x; i < nblocks; i += 256)
        acc += partial[i];

#pragma unroll
    for (int off = 32; off > 0; off >>= 1)
        acc += __shfl_down(acc, off, 64);

    __shared__ float smem[4];
    int lane = threadIdx.x & 63;
    int wid  = threadIdx.x >> 6;
    if (lane == 0) smem[wid] = acc;
    __syncthreads();
    if (threadIdx.x == 0)
        out[0] = (smem[0] + smem[1] + smem[2] + smem[3]) * inv_count;
}

extern "C" void kernel_launch(void* const* d_in, const int* in_sizes, int n_in,
                              void* d_out, int out_size, void* d_ws, size_t ws_size,
                              hipStream_t stream) {
    const float* logits = (const float*)d_in[0];
    const int*   target = (const int*)d_in[1];
    long long n = (long long)in_sizes[0];     // N*C = 41,943,040
    long long nvec = n / 4;

    float* partial = (float*)d_ws;
    const int nblocks = 1024;                 // 4 blocks/CU, 160 KB/stream
    const int nthreads = 256;

    focal_partial_kernel<<<nblocks, nthreads, 0, stream>>>(
        (const f32x4*)logits, (const i32x4*)target, partial, nvec,
        logits, target, n);
    focal_final_kernel<<<1, nthreads, 0, stream>>>(
        partial, nblocks, 1.0f / (float)n, (float*)d_out);
}